// Round 2
// baseline (93.287 us; speedup 1.0000x reference)
//
#include <hip/hip_runtime.h>

// Inclusive prefix-compose of rigid transforms along N=32 per batch row.
// x: float[B][32][3][4];  out[b][n] = x[b][0] * ... * x[b][n]  (4x4 homog product)
//
// 4 transforms per lane, 8 lanes per row. Segmented width-8 shuffle scan.
// Global <-> LDS staging (padded stride 13 float4) keeps HBM fully coalesced.

#define BLOCK 256
#define F4C   12   // float4 per chunk (4 transforms * 3 float4)
#define LSTR  13   // padded LDS stride in float4

struct Xf {
    float a00,a01,a02,a03;   // r00 r01 r02 tx
    float a10,a11,a12,a13;   // r10 r11 r12 ty
    float a20,a21,a22,a23;   // r20 r21 r22 tz
};

__device__ __forceinline__ Xf compose(const Xf& A, const Xf& B) {
    Xf D;
    D.a00 = fmaf(A.a00,B.a00, fmaf(A.a01,B.a10, A.a02*B.a20));
    D.a01 = fmaf(A.a00,B.a01, fmaf(A.a01,B.a11, A.a02*B.a21));
    D.a02 = fmaf(A.a00,B.a02, fmaf(A.a01,B.a12, A.a02*B.a22));
    D.a03 = fmaf(A.a00,B.a03, fmaf(A.a01,B.a13, fmaf(A.a02,B.a23, A.a03)));
    D.a10 = fmaf(A.a10,B.a00, fmaf(A.a11,B.a10, A.a12*B.a20));
    D.a11 = fmaf(A.a10,B.a01, fmaf(A.a11,B.a11, A.a12*B.a21));
    D.a12 = fmaf(A.a10,B.a02, fmaf(A.a11,B.a12, A.a12*B.a22));
    D.a13 = fmaf(A.a10,B.a03, fmaf(A.a11,B.a13, fmaf(A.a12,B.a23, A.a13)));
    D.a20 = fmaf(A.a20,B.a00, fmaf(A.a21,B.a10, A.a22*B.a20));
    D.a21 = fmaf(A.a20,B.a01, fmaf(A.a21,B.a11, A.a22*B.a21));
    D.a22 = fmaf(A.a20,B.a02, fmaf(A.a21,B.a12, A.a22*B.a22));
    D.a23 = fmaf(A.a20,B.a03, fmaf(A.a21,B.a13, fmaf(A.a22,B.a23, A.a23)));
    return D;
}

__device__ __forceinline__ Xf shfl_up_xf(const Xf& V, int d) {
    Xf U;
    U.a00 = __shfl_up(V.a00, d, 8);  U.a01 = __shfl_up(V.a01, d, 8);
    U.a02 = __shfl_up(V.a02, d, 8);  U.a03 = __shfl_up(V.a03, d, 8);
    U.a10 = __shfl_up(V.a10, d, 8);  U.a11 = __shfl_up(V.a11, d, 8);
    U.a12 = __shfl_up(V.a12, d, 8);  U.a13 = __shfl_up(V.a13, d, 8);
    U.a20 = __shfl_up(V.a20, d, 8);  U.a21 = __shfl_up(V.a21, d, 8);
    U.a22 = __shfl_up(V.a22, d, 8);  U.a23 = __shfl_up(V.a23, d, 8);
    return U;
}

__device__ __forceinline__ Xf unpack(const float4& v0, const float4& v1, const float4& v2) {
    Xf T;
    T.a00=v0.x; T.a01=v0.y; T.a02=v0.z; T.a03=v0.w;
    T.a10=v1.x; T.a11=v1.y; T.a12=v1.z; T.a13=v1.w;
    T.a20=v2.x; T.a21=v2.y; T.a22=v2.z; T.a23=v2.w;
    return T;
}

__global__ __launch_bounds__(BLOCK) void compose_scan4(
    const float4* __restrict__ x, float4* __restrict__ out, long long total_f4)
{
    __shared__ float4 lds[BLOCK * LSTR];   // 53.25 KB
    const int tid = threadIdx.x;
    const long long blk_base = (long long)blockIdx.x * (BLOCK * F4C);

    // ---- 1. coalesced global -> LDS (padded chunk layout) ----
    #pragma unroll
    for (int j = 0; j < F4C; ++j) {
        const int l = tid + j * BLOCK;          // block-local f4 index
        const long long g = blk_base + l;
        const int c = l / F4C;                  // block-local chunk
        const int r = l - c * F4C;
        if (g < total_f4) lds[c * LSTR + r] = x[g];
    }
    __syncthreads();

    // ---- 2. read own chunk (4 transforms) ----
    float4 v[F4C];
    #pragma unroll
    for (int j = 0; j < F4C; ++j) v[j] = lds[tid * LSTR + j];

    Xf c0 = unpack(v[0], v[1], v[2]);
    Xf c1 = unpack(v[3], v[4], v[5]);
    Xf c2 = unpack(v[6], v[7], v[8]);
    Xf c3 = unpack(v[9], v[10], v[11]);

    // ---- 3. serial inclusive compose within the chunk ----
    c1 = compose(c0, c1);
    c2 = compose(c1, c2);
    c3 = compose(c2, c3);

    // ---- 4. segmented (width-8) scan of chunk products ----
    const int sl = tid & 7;                    // lane within row segment
    Xf p = c3;
    #pragma unroll
    for (int d = 1; d < 8; d <<= 1) {
        Xf u = shfl_up_xf(p, d);
        Xf np = compose(u, p);
        if (sl >= d) p = np;
    }
    // exclusive prefix of this lane's chunk
    Xf e = shfl_up_xf(p, 1);
    if (sl == 0) {
        e.a00=1.f; e.a01=0.f; e.a02=0.f; e.a03=0.f;
        e.a10=0.f; e.a11=1.f; e.a12=0.f; e.a13=0.f;
        e.a20=0.f; e.a21=0.f; e.a22=1.f; e.a23=0.f;
    }

    // ---- 5. apply exclusive prefix to local inclusive values ----
    Xf o0 = compose(e, c0);
    Xf o1 = compose(e, c1);
    Xf o2 = compose(e, c2);
    Xf o3 = compose(e, c3);

    // ---- 6. pack outputs back to own LDS slots ----
    v[0]=make_float4(o0.a00,o0.a01,o0.a02,o0.a03);
    v[1]=make_float4(o0.a10,o0.a11,o0.a12,o0.a13);
    v[2]=make_float4(o0.a20,o0.a21,o0.a22,o0.a23);
    v[3]=make_float4(o1.a00,o1.a01,o1.a02,o1.a03);
    v[4]=make_float4(o1.a10,o1.a11,o1.a12,o1.a13);
    v[5]=make_float4(o1.a20,o1.a21,o1.a22,o1.a23);
    v[6]=make_float4(o2.a00,o2.a01,o2.a02,o2.a03);
    v[7]=make_float4(o2.a10,o2.a11,o2.a12,o2.a13);
    v[8]=make_float4(o2.a20,o2.a21,o2.a22,o2.a23);
    v[9]=make_float4(o3.a00,o3.a01,o3.a02,o3.a03);
    v[10]=make_float4(o3.a10,o3.a11,o3.a12,o3.a13);
    v[11]=make_float4(o3.a20,o3.a21,o3.a22,o3.a23);
    #pragma unroll
    for (int j = 0; j < F4C; ++j) lds[tid * LSTR + j] = v[j];
    __syncthreads();

    // ---- 7. coalesced LDS -> global ----
    #pragma unroll
    for (int j = 0; j < F4C; ++j) {
        const int l = tid + j * BLOCK;
        const long long g = blk_base + l;
        const int c = l / F4C;
        const int r = l - c * F4C;
        if (g < total_f4) out[g] = lds[c * LSTR + r];
    }
}

extern "C" void kernel_launch(void* const* d_in, const int* in_sizes, int n_in,
                              void* d_out, int out_size, void* d_ws, size_t ws_size,
                              hipStream_t stream) {
    const float4* x = (const float4*)d_in[0];
    float4* out = (float4*)d_out;

    const long long nrows = in_sizes[0] / 384;          // B (32 * 12 floats per row)
    const long long nchunks = nrows * 8;                // 4 transforms per chunk
    const long long total_f4 = nchunks * F4C;
    const int grid = (int)((nchunks + BLOCK - 1) / BLOCK);

    compose_scan4<<<grid, BLOCK, 0, stream>>>(x, out, total_f4);
}